// Round 17
// baseline (58.387 us; speedup 1.0000x reference)
//
#include <hip/hip_runtime.h>

#define NIN 64
#define NOUT 64
#define NTO 16
#define HH 192
#define WW 192
#define HO 190
#define WO 190
#define WBUF 5120            // per-wave buffer: 18 rows x 17 units(16B) = 4896 B + pad
#define NBLK 2304            // 36 groups (9 tiles x 4 batch) x 64 out channels

typedef const __attribute__((address_space(1))) void gv_t;
typedef __attribute__((address_space(3))) void lv_t;

__global__ __launch_bounds__(256, 4) void scm_kernel(
    const float* __restrict__ x,
    const float* __restrict__ w,
    const float* __restrict__ bias,
    const int* __restrict__ conn_in,
    float* __restrict__ out)
{
    __shared__ char smem[4 * 2 * WBUF];   // 40960 B: 4 waves x (A,B) wave-private buffers

    const int tid  = threadIdx.x;
    const int lane = tid & 63;
    const int tx   = tid & 15;       // col group of 4
    const int ty   = tid >> 4;       // row group of 4 (block-wide)
    const int wv   = ty >> 2;        // wave id 0..3 (rows 16*wv .. +15)
    const int lty  = ty & 3;         // row group within wave

    // XCD-aware swizzle (bijective, 2304 % 8 == 0), o-minor for L2 gather reuse.
    const int lid = (blockIdx.x & 7) * (NBLK / 8) + (blockIdx.x >> 3);
    const int o   = lid & 63;
    const int g   = lid >> 6;        // 0..35
    const int tile = g % 9;
    const int b    = g / 9;
    const int i0 = (tile / 3) * 64;
    const int j0 = (tile % 3) * 64;

    // ---- Wave-private LDS layout per buffer: 18 rows x 17 units of 16B
    // (272 B row stride, halo inline as unit 16; bytes 4896.. = pad).
    // 272 B stride => successive lty groups start at banks 0/16/0/16:
    // 2-way aliasing (free, m136) instead of 256B-stride's 4-way.
    // Staged by 5 width-16 DMA rounds; physical unit u = s*64+lane.
    // Clamped slots feed only outputs >= row/col 190 (discarded).
    int goff[5];
    #pragma unroll
    for (int s = 0; s < 5; ++s) {
        int u = s * 64 + lane;
        int gr, gc;
        if (u < 306) {
            int row = u / 17;
            int uc  = u - row * 17;
            gr = i0 + 16 * wv + row;
            gc = j0 + 4 * uc; if (gc > 188) gc = 188;
        } else { gr = 191; gc = 0; }
        if (gr > 191) gr = 191;
        goff[s] = (gr * WW + gc) * 4;
    }

    // Read offsets (channel-independent):
    //   A = float4 cols 4tx..+3  at row lr, unit tx
    //   B = float2 cols 4tx+4,+5 = first 8B of unit tx+1 (unit 16 = inline halo)
    int offA[6], offB[6];
    #pragma unroll
    for (int r = 0; r < 6; ++r) {
        int lr = lty * 4 + r;
        offA[r] = lr * 272 + tx * 16;
        offB[r] = offA[r] + 16;
    }

    char* bufA = smem + wv * (2 * WBUF);
    char* bufB = bufA + WBUF;
    const char* xb = (const char*)x + (size_t)b * NIN * HH * WW * 4;
    const int kbase = o * NTO;

    float acc[4][4];
    #pragma unroll
    for (int i = 0; i < 4; ++i)
        #pragma unroll
        for (int p = 0; p < 4; ++p) acc[i][p] = 0.f;

    // Full-patch read registers (static names).
    float4 p0, p1, p2, p3, p4, p5;
    float2 q0, q1, q2, q3, q4, q5;
    float wv9[9];

#define STAGE(t, lb) do {                                                      \
        const int _ci = __builtin_amdgcn_readfirstlane(conn_in[kbase + (t)]);  \
        const char* _src = xb + (size_t)_ci * (HH * WW * 4);                   \
        _Pragma("unroll")                                                      \
        for (int _s = 0; _s < 5; ++_s)                                         \
            __builtin_amdgcn_global_load_lds((gv_t*)(_src + goff[_s]),         \
                                             (lv_t*)((lb) + _s * 1024),        \
                                             16, 0, 0);                        \
    } while (0)

#define READS(rb) do {                                                         \
        p0 = *(const float4*)((rb) + offA[0]); q0 = *(const float2*)((rb) + offB[0]); \
        p1 = *(const float4*)((rb) + offA[1]); q1 = *(const float2*)((rb) + offB[1]); \
        p2 = *(const float4*)((rb) + offA[2]); q2 = *(const float2*)((rb) + offB[2]); \
        p3 = *(const float4*)((rb) + offA[3]); q3 = *(const float2*)((rb) + offB[3]); \
        p4 = *(const float4*)((rb) + offA[4]); q4 = *(const float2*)((rb) + offB[4]); \
        p5 = *(const float4*)((rb) + offA[5]); q5 = *(const float2*)((rb) + offB[5]); \
    } while (0)

#define ROWF(r, P, Q) do {                                                     \
        const float _rv[6] = {P.x, P.y, P.z, P.w, Q.x, Q.y};                   \
        _Pragma("unroll")                                                      \
        for (int _i = 0; _i < 4; ++_i) {                                       \
            const int _kh = (r) - _i;                                          \
            if (_kh >= 0 && _kh < 3) {                                         \
                _Pragma("unroll")                                              \
                for (int _kw = 0; _kw < 3; ++_kw) {                            \
                    const float _wk = wv9[_kh * 3 + _kw];                      \
                    _Pragma("unroll")                                          \
                    for (int _p = 0; _p < 4; ++_p)                             \
                        acc[_i][_p] = fmaf(_wk, _rv[_p + _kw], acc[_i][_p]);   \
                }                                                              \
            }                                                                  \
        }                                                                      \
    } while (0)

#define ALLROWS() do { ROWF(0,p0,q0); ROWF(1,p1,q1); ROWF(2,p2,q2);            \
                       ROWF(3,p3,q3); ROWF(4,p4,q4); ROWF(5,p5,q5); } while (0)

    // prologue: channels 0,1 in flight
    STAGE(0, bufA);
    STAGE(1, bufB);

    #pragma unroll 1
    for (int tt = 0; tt < 8; ++tt) {
        const int tA = 2 * tt, tB = 2 * tt + 1;

        // ---------- even channel (buffer A) ----------
        #pragma unroll
        for (int q = 0; q < 9; ++q) wv9[q] = w[(kbase + tA) * 9 + q];
        asm volatile("s_waitcnt vmcnt(5)" ::: "memory");   // A's DMA done (B's 5 fly)
        __builtin_amdgcn_sched_barrier(0);
        READS(bufA);                                        // 12 ds_reads back-to-back
        asm volatile("s_waitcnt lgkmcnt(0)" ::: "memory");  // reads landed in regs
        __builtin_amdgcn_sched_barrier(0);
        if (tt < 7) STAGE(tA + 2, bufA);                    // refill A under compute
        ALLROWS();

        // ---------- odd channel (buffer B) ----------
        #pragma unroll
        for (int q = 0; q < 9; ++q) wv9[q] = w[(kbase + tB) * 9 + q];
        if (tt < 7) asm volatile("s_waitcnt vmcnt(5)" ::: "memory");
        else        asm volatile("s_waitcnt vmcnt(0)" ::: "memory");
        __builtin_amdgcn_sched_barrier(0);
        READS(bufB);
        asm volatile("s_waitcnt lgkmcnt(0)" ::: "memory");
        __builtin_amdgcn_sched_barrier(0);
        if (tt < 7) STAGE(tB + 2, bufB);
        ALLROWS();
    }
#undef STAGE
#undef READS
#undef ROWF
#undef ALLROWS

    const float bv = bias[o];
    float* outp = out + (size_t)(b * NOUT + o) * (HO * WO);
    #pragma unroll
    for (int i = 0; i < 4; ++i) {
        const int gi = i0 + ty * 4 + i;
        if (gi < HO) {
            const int gj = j0 + tx * 4;
            float* row = outp + (size_t)gi * WO + gj;
            if (gj + 3 < WO) {
                *(float2*)(row)     = make_float2(acc[i][0] + bv, acc[i][1] + bv);
                *(float2*)(row + 2) = make_float2(acc[i][2] + bv, acc[i][3] + bv);
            } else {
                #pragma unroll
                for (int p = 0; p < 4; ++p)
                    if (gj + p < WO) row[p] = acc[i][p] + bv;
            }
        }
    }
}

extern "C" void kernel_launch(void* const* d_in, const int* in_sizes, int n_in,
                              void* d_out, int out_size, void* d_ws, size_t ws_size,
                              hipStream_t stream) {
    const float* x       = (const float*)d_in[0];
    const float* weight  = (const float*)d_in[1];
    const float* bias    = (const float*)d_in[2];
    const int*   conn_in = (const int*)d_in[3];
    // d_in[4] = conn_out (implicit: k -> k/16)

    dim3 grid(NBLK);
    dim3 block(256);
    scm_kernel<<<grid, block, 0, stream>>>(x, weight, bias, conn_in, (float*)d_out);
}

// Round 18
// 48.462 us; speedup vs baseline: 1.2048x; 1.2048x over previous
//
#include <hip/hip_runtime.h>
#include <hip/hip_bf16.h>

#define HH 192
#define WW 192
#define HOUT 190
#define NCH 64
#define W2_N (64 * 9 * 64)

typedef __attribute__((ext_vector_type(8))) short bf16x8;
typedef __attribute__((ext_vector_type(4))) float f32x4;

static __device__ __forceinline__ ushort f2bf(float f) {
    __hip_bfloat16 h = __float2bfloat16(f);   // RNE
    return *reinterpret_cast<ushort*>(&h);
}

// W2[o][tap][c] = sum_t (conn[o*16+t]==c) * w[(o*16+t)*9 + tap], bf16.
__global__ __launch_bounds__(256) void build_w2(const float* __restrict__ w,
                                                const int* __restrict__ conn,
                                                ushort* __restrict__ w2) {
    int idx = blockIdx.x * 256 + threadIdx.x;
    if (idx >= W2_N) return;
    int o = idx / 576, rem = idx - o * 576, tap = rem >> 6, c = rem & 63;
    float s = 0.f;
    #pragma unroll
    for (int t = 0; t < 16; ++t) {
        int k = o * 16 + t;
        if (conn[k] == c) s += w[k * 9 + tap];
    }
    w2[idx] = f2bf(s);
}

// Dense 64->64 3x3 conv via mfma_f32_16x16x32_bf16, tap-outer implicit GEMM.
// Block: 16x16 output pixels x 64 outch. 4 waves, wave w = outch 16w..16w+15.
// LDS x-tile: [18 rows][18 cols][64 ch] bf16, col stride 72 ushort (144 B):
// stride/16B = 9 (odd) -> A-frag b128 reads conflict-free (octet model).
__global__ __launch_bounds__(256, 2) void scm_mfma(
    const float* __restrict__ x,
    const ushort* __restrict__ w2,
    const float* __restrict__ bias,
    float* __restrict__ out)
{
    __shared__ ushort xt[18 * 18 * 72];   // 46,656 B

    const int tid  = threadIdx.x;
    const int lane = tid & 63;
    const int wv   = tid >> 6;
    const int col  = lane & 15;           // A-frag m (pixel col) / B-frag n
    const int g    = lane >> 4;           // k-subgroup

    const int tileid = blockIdx.x;        // 0..143
    const int b      = blockIdx.y;
    const int ti0 = (tileid / 12) * 16;
    const int tj0 = (tileid % 12) * 16;

    // ---- stage + transpose: xt[(r*18+cl)*72 + c] = bf16(x[b][c][ti0+r][tj0+cl])
    // Clamped rows/cols feed only outputs >= 190 (discarded at store).
    {
        const float* xc = x + ((size_t)(b * NCH + lane)) * (HH * WW);
        for (int pr = wv; pr < 90; pr += 4) {      // 18 rows x 5 col-quads
            int r = pr / 5, q = pr - (pr / 5) * 5;
            int gr = ti0 + r;     if (gr > 191) gr = 191;
            int gc = tj0 + 4 * q; if (gc > 188) gc = 188;
            float4 v = *(const float4*)(xc + gr * WW + gc);
            ushort* dst = &xt[(r * 18 + 4 * q) * 72 + lane];
            dst[0]  = f2bf(v.x);
            dst[72] = f2bf(v.y);
            if (q < 4) { dst[144] = f2bf(v.z); dst[216] = f2bf(v.w); }
        }
    }
    __syncthreads();

    // ---- compute
    f32x4 acc[16];
    #pragma unroll
    for (int i = 0; i < 16; ++i) acc[i] = (f32x4){0.f, 0.f, 0.f, 0.f};

    // B base: W2[(16wv+col)][tap][32s+8g..+7] -> elems (16wv+col)*576 + tap*64 + s*32 + 8g
    const ushort* bp  = w2 + (16 * wv + col) * 576 + g * 8;
    // A base: xt[(R*18 + col + kw)*72 + s*32 + 8g]
    const ushort* ap0 = &xt[col * 72 + g * 8];

    #pragma unroll
    for (int s = 0; s < 2; ++s) {
        #pragma unroll
        for (int kw = 0; kw < 3; ++kw) {
            const bf16x8 B0 = *(const bf16x8*)(bp + (0 * 3 + kw) * 64 + s * 32);
            const bf16x8 B1 = *(const bf16x8*)(bp + (1 * 3 + kw) * 64 + s * 32);
            const bf16x8 B2 = *(const bf16x8*)(bp + (2 * 3 + kw) * 64 + s * 32);
            bf16x8 f[18];
            #pragma unroll
            for (int R = 0; R < 18; ++R)
                f[R] = *(const bf16x8*)(ap0 + (R * 18 + kw) * 72 + s * 32);
            #pragma unroll
            for (int Mt = 0; Mt < 16; ++Mt) {
                acc[Mt] = __builtin_amdgcn_mfma_f32_16x16x32_bf16(f[Mt],     B0, acc[Mt], 0, 0, 0);
                acc[Mt] = __builtin_amdgcn_mfma_f32_16x16x32_bf16(f[Mt + 1], B1, acc[Mt], 0, 0, 0);
                acc[Mt] = __builtin_amdgcn_mfma_f32_16x16x32_bf16(f[Mt + 2], B2, acc[Mt], 0, 0, 0);
            }
        }
    }

    // ---- epilogue: D row = 4g+reg -> pixel col tj0+4g+reg; D col = lane&15 -> o.
    const int o = 16 * wv + col;
    const float bv = bias[o];
    #pragma unroll
    for (int Mt = 0; Mt < 16; ++Mt) {
        int row = ti0 + Mt;
        if (row < HOUT) {
            int cj = tj0 + 4 * g;
            float* rp = out + ((size_t)(b * NCH + o) * HOUT + row) * HOUT + cj;
            float v0 = acc[Mt][0] + bv, v1 = acc[Mt][1] + bv;
            float v2 = acc[Mt][2] + bv, v3 = acc[Mt][3] + bv;
            if (cj + 3 < HOUT) {
                *(float2*)(rp)     = make_float2(v0, v1);
                *(float2*)(rp + 2) = make_float2(v2, v3);
            } else {
                if (cj     < HOUT) rp[0] = v0;
                if (cj + 1 < HOUT) rp[1] = v1;
                if (cj + 2 < HOUT) rp[2] = v2;
                if (cj + 3 < HOUT) rp[3] = v3;
            }
        }
    }
}

extern "C" void kernel_launch(void* const* d_in, const int* in_sizes, int n_in,
                              void* d_out, int out_size, void* d_ws, size_t ws_size,
                              hipStream_t stream) {
    const float* x       = (const float*)d_in[0];
    const float* weight  = (const float*)d_in[1];
    const float* bias    = (const float*)d_in[2];
    const int*   conn_in = (const int*)d_in[3];
    // d_in[4] = conn_out (implicit: k -> k/16)

    ushort* w2 = (ushort*)d_ws;   // 73,728 B

    build_w2<<<dim3((W2_N + 255) / 256), dim3(256), 0, stream>>>(weight, conn_in, w2);

    dim3 grid(144, 4);            // 12x12 pixel tiles x 4 batches
    scm_mfma<<<grid, dim3(256), 0, stream>>>(x, w2, bias, (float*)d_out);
}